// Round 15
// baseline (381.852 us; speedup 1.0000x reference)
//
#include <hip/hip_runtime.h>
#include <hip/hip_bf16.h>
#include <math.h>

// ---------------------------------------------------------------------------
// AttentionBlock: y[b,e] = sum_s w[b,s] * (x_bs @ V_s),
//   w = scores / ||scores||_2,  scores[b,s] = x_bs^T (Q_s K_s^T) x_bs
// Round 15: R13 base (best, 351.3us; R14's intra-XCD atomics regressed ->
// reverted). ONE change: k_out K-loop pipelined (T3 minimum 2-phase):
//   - double-buffered LDS (80KB, 2 blocks/CU)
//   - next tile's A (regs) + B (gload_lds) issued BEFORE current MFMA
//   - weight-mul + A ds_write after MFMA (T14 issue-early/write-late)
//   - ONE __syncthreads per K-step (was 2 + full drain before compute)
// ---------------------------------------------------------------------------

typedef __attribute__((ext_vector_type(8))) short s8v;   // 8 x bf16 bits
typedef __attribute__((ext_vector_type(4))) float f4v;   // 4 x f32

#define MFMA_BF16(a, b, c) __builtin_amdgcn_mfma_f32_16x16x32_bf16((a), (b), (c), 0, 0, 0)

constexpr int NB = 4096;     // batch
constexpr int NS = 32;       // segments
constexpr int ND = 512;      // d per segment
constexpr int NE = 512;      // e (output dim)
constexpr int SD = NS * ND;  // 16384

__device__ __forceinline__ short f2bf(float f) {
  union { float f; unsigned u; } v; v.f = f;
  unsigned r = v.u + 0x7fffu + ((v.u >> 16) & 1u);  // RNE
  return (short)(r >> 16);
}
__device__ __forceinline__ float bf2f(short h) {
  union { unsigned u; float f; } v; v.u = ((unsigned)(unsigned short)h) << 16;
  return v.f;
}
__device__ __forceinline__ s8v cvt8(const float* p) {
  s8v r;
#pragma unroll
  for (int i = 0; i < 8; ++i) r[i] = f2bf(p[i]);
  return r;
}

// global -> LDS direct (16B per lane). LDS base must be wave-uniform;
// hardware writes base + lane*16 for the wave's 64 lanes.
__device__ __forceinline__ void gload16(const void* g, void* l) {
  __builtin_amdgcn_global_load_lds(
      (const __attribute__((address_space(1))) unsigned int*)g,
      (__attribute__((address_space(3))) unsigned int*)l, 16, 0, 0);
}

// ---------------------------------------------------------------------------
// K_castx: x f32 -> xb bf16 (one vec8/thread, zero LDS) + zero scores
// ---------------------------------------------------------------------------
__global__ __launch_bounds__(256) void k_castx(const float* __restrict__ x,
                                               short* __restrict__ xb,
                                               float* __restrict__ scores) {
  size_t gtid = (size_t)blockIdx.x * 256 + threadIdx.x;
  if (gtid < (size_t)NB * NS / 4) {           // 32768 threads x 4 floats
    f4v z = (f4v)0.0f;
    *(f4v*)(scores + gtid * 4) = z;
  }
  size_t i = gtid * 8;                        // covers exactly NB*SD = 67.1M
  f4v a = *(const f4v*)(x + i);
  f4v b = *(const f4v*)(x + i + 4);
  s8v o;
#pragma unroll
  for (int u = 0; u < 4; ++u) { o[u] = f2bf(a[u]); o[4 + u] = f2bf(b[u]); }
  *(s8v*)(xb + i) = o;
}

// ---------------------------------------------------------------------------
// K_misc: [0,512) gram | [512,2560) transposeV
// ---------------------------------------------------------------------------
__global__ __launch_bounds__(256) void k_misc(const float* __restrict__ V,
                                              short* __restrict__ Vt,
                                              const float* __restrict__ Kw,
                                              const float* __restrict__ Qw,
                                              short* __restrict__ G) {
  __shared__ __align__(16) char smem[36864];
  int bid = blockIdx.x;
  int tid = threadIdx.x;

  if (bid >= 512) {
    // ---- transposeV: V [SD,NE] f32 -> Vt [NE,SD] bf16 ----
    float (*t)[65] = (float(*)[65])smem;
    int t2 = bid - 512;
    int k0 = (t2 & 255) * 64;
    int e0 = (t2 >> 8) * 64;
#pragma unroll
    for (int i = 0; i < 16; ++i) {
      int idx = tid + 256 * i;
      int r = idx >> 6, c = idx & 63;
      t[r][c] = V[(size_t)(k0 + r) * NE + e0 + c];
    }
    __syncthreads();
#pragma unroll
    for (int i = 0; i < 16; ++i) {
      int idx = tid + 256 * i;
      int e = idx >> 6, k = idx & 63;
      Vt[(size_t)(e0 + e) * SD + k0 + k] = f2bf(t[k][e]);
    }
  } else {
    // ---- gram: G_s[i][j] = sum_e K_s[i,e] * Q_s[j,e], 128x128 tile ----
    int t3 = bid;
    int s = t3 >> 4;
    int tm = (t3 >> 2) & 3, tn = t3 & 3;
    const float* A = Kw + (size_t)s * ND * NE + (size_t)tm * 128 * NE;
    const float* B = Qw + (size_t)s * ND * NE + (size_t)tn * 128 * NE;
    short* Gs = G + (size_t)s * ND * ND;

    s8v (*lsA)[9] = (s8v(*)[9])smem;
    s8v (*lsB)[9] = (s8v(*)[9])(smem + 18432);

    int lane = tid & 63, wid = tid >> 6;
    int wr = wid >> 1, wc = wid & 1;
    int lhi = lane >> 4, llo = lane & 15;

    float ra[4][8], rb[4][8];
    f4v acc[4][4];
#pragma unroll
    for (int i = 0; i < 4; ++i)
#pragma unroll
      for (int j = 0; j < 4; ++j) acc[i][j] = (f4v)0.0f;

    auto loadRegs = [&](int k0) {
#pragma unroll
      for (int i = 0; i < 4; ++i) {
        int c = tid + 256 * i; int row = c >> 3, k8 = c & 7;
        const float* p = A + (size_t)row * NE + k0 + k8 * 8;
        *(f4v*)&ra[i][0] = *(const f4v*)p;
        *(f4v*)&ra[i][4] = *(const f4v*)(p + 4);
        const float* q = B + (size_t)row * NE + k0 + k8 * 8;
        *(f4v*)&rb[i][0] = *(const f4v*)q;
        *(f4v*)&rb[i][4] = *(const f4v*)(q + 4);
      }
    };
    auto writeLds = [&]() {
#pragma unroll
      for (int i = 0; i < 4; ++i) {
        int c = tid + 256 * i; int row = c >> 3, k8 = c & 7;
        lsA[row][k8] = cvt8(ra[i]);
        lsB[row][k8] = cvt8(rb[i]);
      }
    };

    loadRegs(0);
    writeLds();
    for (int kt = 0; kt < 8; ++kt) {
      __syncthreads();
      if (kt + 1 < 8) loadRegs((kt + 1) * 64);
#pragma unroll
      for (int kk = 0; kk < 2; ++kk) {
        s8v af[4], bq[4];
#pragma unroll
        for (int i = 0; i < 4; ++i) af[i] = lsA[wr * 64 + i * 16 + llo][kk * 4 + lhi];
#pragma unroll
        for (int j = 0; j < 4; ++j) bq[j] = lsB[wc * 64 + j * 16 + llo][kk * 4 + lhi];
#pragma unroll
        for (int i = 0; i < 4; ++i)
#pragma unroll
          for (int j = 0; j < 4; ++j) acc[i][j] = MFMA_BF16(af[i], bq[j], acc[i][j]);
      }
      __syncthreads();
      if (kt + 1 < 8) writeLds();
    }

#pragma unroll
    for (int i = 0; i < 4; ++i)
#pragma unroll
      for (int r = 0; r < 4; ++r) {
        int row = tm * 128 + wr * 64 + i * 16 + lhi * 4 + r;
#pragma unroll
        for (int j = 0; j < 4; ++j) {
          int col = tn * 128 + wc * 64 + j * 16 + llo;
          Gs[(size_t)row * ND + col] = f2bf(acc[i][j][r]);
        }
      }
  }
}

// ---------------------------------------------------------------------------
// K_symm: U[a][b] = a<b ? G[a][b]+G[b][a] : (a==b ? G[a][a] : 0)
// ---------------------------------------------------------------------------
__global__ __launch_bounds__(256) void k_symm(const short* __restrict__ G,
                                              short* __restrict__ U) {
  int s = blockIdx.y;
  int kt = blockIdx.x >> 3, nt = blockIdx.x & 7;
  const short* Gs = G + (size_t)s * ND * ND;
  short* Us = U + (size_t)s * ND * ND;
  int k0 = kt * 64, n0 = nt * 64;
  int tid = threadIdx.x;
  int r = tid >> 2, cb = (tid & 3) * 16;

  if (kt > nt) {  // strictly below diagonal: zero
    s8v z = (s8v)(short)0;
    *(s8v*)&Us[(size_t)(k0 + r) * ND + n0 + cb] = z;
    *(s8v*)&Us[(size_t)(k0 + r) * ND + n0 + cb + 8] = z;
    return;
  }

  // tt[j][i] = G[n0+j][k0+i]
  __shared__ float tt[64][65];
  {
    const short* src = &Gs[(size_t)(n0 + r) * ND + k0 + cb];
    s8v a = *(const s8v*)src;
    s8v b = *(const s8v*)(src + 8);
#pragma unroll
    for (int u = 0; u < 8; ++u) { tt[r][cb + u] = bf2f(a[u]); tt[r][cb + 8 + u] = bf2f(b[u]); }
  }
  __syncthreads();
  {
    const short* src = &Gs[(size_t)(k0 + r) * ND + n0 + cb];
    s8v a = *(const s8v*)src;
    s8v b = *(const s8v*)(src + 8);
    s8v oa, ob;
#pragma unroll
    for (int u = 0; u < 8; ++u) {
      int k = k0 + r;
      int n1 = n0 + cb + u, n2 = n0 + cb + 8 + u;
      float g1 = bf2f(a[u]), g2 = bf2f(b[u]);
      float v1 = (k < n1) ? (g1 + tt[cb + u][r]) : ((k == n1) ? g1 : 0.f);
      float v2 = (k < n2) ? (g2 + tt[cb + 8 + u][r]) : ((k == n2) ? g2 : 0.f);
      oa[u] = f2bf(v1); ob[u] = f2bf(v2);
    }
    short* dst = &Us[(size_t)(k0 + r) * ND + n0 + cb];
    *(s8v*)dst = oa;
    *(s8v*)(dst + 8) = ob;
  }
}

// ---------------------------------------------------------------------------
// K3: T = Xb_s @ W (W[k][n] = U[n][k], nonzero k >= n),
//     scores[b,s] += sum_n Xb_s[b,n]*T[b,n]
//     256x128 tile, 8 waves (512 thr), BK=64, K-loop kt in [2*nt, 8)
// ---------------------------------------------------------------------------
__global__ __launch_bounds__(512, 4) void k_scores(const short* __restrict__ xb,
                                                   const short* __restrict__ U,
                                                   float* __restrict__ scores) {
  // grid 2048 = 32 s x 16 mt x 4 nt, XCD-chunked by s
  int t = blockIdx.x;
  int swz = (t & 7) * 256 + (t >> 3);     // bijective, 2048 % 8 == 0
  int s = swz >> 6;
  int mt = (swz >> 2) & 15;
  int nt = swz & 3;
  int b0 = mt * 256, n0 = nt * 128;
  const short* Asrc = xb + (size_t)b0 * SD + s * ND;              // LD = SD
  const short* Bt = U + (size_t)s * ND * ND + (size_t)n0 * ND;    // rows = n

  __shared__ __align__(16) short lsA[256 * 64];   // 32 KB
  __shared__ __align__(16) short lsB[128 * 64];   // 16 KB

  int tid = threadIdx.x;
  int lane = tid & 63, wid = tid >> 6;            // 8 waves
  int wr = wid >> 1, wc = wid & 1;                // 4 x 2 wave grid
  int lhi = lane >> 4, llo = lane & 15;
  int lrow = lane >> 3, lcol = (lane & 7) * 8;

  f4v acc[4][4];
#pragma unroll
  for (int i = 0; i < 4; ++i)
#pragma unroll
    for (int j = 0; j < 4; ++j) acc[i][j] = (f4v)0.0f;

  for (int kt = 2 * nt; kt < 8; ++kt) {
    int k0 = kt * 64;
    // A: 32 chunks of 8 rows (4 per wave); B: 16 chunks (2 per wave)
#pragma unroll
    for (int c = 0; c < 4; ++c) {
      int chunk = wid * 4 + c;                 // 0..31
      int row = chunk * 8 + lrow;
      gload16(Asrc + (size_t)row * SD + k0 + lcol, (char*)lsA + chunk * 1024);
    }
#pragma unroll
    for (int c = 0; c < 2; ++c) {
      int chunk = wid * 2 + c;                 // 0..15
      int row = chunk * 8 + lrow;
      gload16(Bt + (size_t)row * ND + k0 + lcol, (char*)lsB + chunk * 1024);
    }
    __syncthreads();
    const s8v* fA = (const s8v*)lsA;
    const s8v* fB = (const s8v*)lsB;
#pragma unroll
    for (int kk = 0; kk < 2; ++kk) {
      s8v af[4], bq[4];
#pragma unroll
      for (int i = 0; i < 4; ++i) af[i] = fA[(wr * 64 + i * 16 + llo) * 8 + kk * 4 + lhi];
#pragma unroll
      for (int j = 0; j < 4; ++j) bq[j] = fB[(wc * 64 + j * 16 + llo) * 8 + kk * 4 + lhi];
#pragma unroll
      for (int i = 0; i < 4; ++i)
#pragma unroll
        for (int j = 0; j < 4; ++j) acc[i][j] = MFMA_BF16(af[i], bq[j], acc[i][j]);
    }
    __syncthreads();
  }

  // Fused epilogue: scores[b,s] += sum over this block's n-range of x*T
#pragma unroll
  for (int i = 0; i < 4; ++i)
#pragma unroll
    for (int r = 0; r < 4; ++r) {
      int rowl = wr * 64 + i * 16 + lhi * 4 + r;
      int b = b0 + rowl;
      const short* xr = xb + (size_t)b * SD + s * ND + n0 + wc * 64;
      float v = 0.f;
#pragma unroll
      for (int j = 0; j < 4; ++j) v += bf2f(xr[j * 16 + llo]) * acc[i][j][r];
      v += __shfl_xor(v, 1);
      v += __shfl_xor(v, 2);
      v += __shfl_xor(v, 4);
      v += __shfl_xor(v, 8);
      if (llo == 0) atomicAdd(&scores[b * NS + s], v);
    }
}

// ---------------------------------------------------------------------------
// K4: weights = scores / ||scores||_2   (grid 16 x 256 = NB threads)
// ---------------------------------------------------------------------------
__global__ __launch_bounds__(256) void k_weights(const float* __restrict__ scores,
                                                 float* __restrict__ w) {
  int b = blockIdx.x * 256 + threadIdx.x;
  float sq = 0.f, sc[NS];
#pragma unroll
  for (int s = 0; s < NS; ++s) { sc[s] = scores[b * NS + s]; sq += sc[s] * sc[s]; }
  float inv = 1.0f / sqrtf(sq);
#pragma unroll
  for (int s = 0; s < NS; ++s) w[b * NS + s] = sc[s] * inv;
}

// ---------------------------------------------------------------------------
// K5: y_part[kg] = (w (.) xb)_kg @ Vt^T_kg   64x256 tile, BK=64, kg = XCD
//     PIPELINED: double-buffered LDS (80KB), next-tile A(regs)+B(gload_lds)
//     issued before current MFMA; weight-mul + A ds_write after MFMA;
//     one __syncthreads per K-step. Non-atomic y_part stores (R13).
// ---------------------------------------------------------------------------
__global__ __launch_bounds__(256, 2) void k_out(const short* __restrict__ xb,
                                                const float* __restrict__ wts,
                                                const short* __restrict__ Vt,
                                                float* __restrict__ y_part) {
  int t0 = blockIdx.x;
  int kg = t0 & 7;               // fastest -> XCD id
  int nt = (t0 >> 3) & 1;
  int mt = t0 >> 4;
  int b0 = mt * 64, n0 = nt * 256;
  const short* Asrc = xb + (size_t)b0 * SD + kg * 2048;
  const short* Bsrc = Vt + (size_t)n0 * SD + kg * 2048;   // 256 e-rows, LD = SD
  float* yp = y_part + (size_t)kg * NB * NE;

  __shared__ __align__(16) short lsA[2][64 * 64];    // 2 x 8 KB
  __shared__ __align__(16) short lsB[2][256 * 64];   // 2 x 32 KB

  int tid = threadIdx.x;
  int lane = tid & 63, wid = tid >> 6;            // 4 waves: 1M x 4N
  int lhi = lane >> 4, llo = lane & 15;

  int arow0 = tid >> 3;            // 0..31
  int arow1 = 32 + (tid >> 3);     // 32..63
  int acb = (tid & 7) * 8;         // col offset (elements)

  // preload the 4 per-sl weights for this thread's two A rows
  float w0v[4], w1v[4];
#pragma unroll
  for (int sl = 0; sl < 4; ++sl) {
    w0v[sl] = wts[(b0 + arow0) * NS + kg * 4 + sl];
    w1v[sl] = wts[(b0 + arow1) * NS + kg * 4 + sl];
  }

  f4v acc[4][4];
#pragma unroll
  for (int i = 0; i < 4; ++i)
#pragma unroll
    for (int j = 0; j < 4; ++j) acc[i][j] = (f4v)0.0f;

  auto bstage = [&](int buf, int k0) {
#pragma unroll
    for (int c = 0; c < 8; ++c) {
      int chunk = wid * 8 + c;           // 0..31 -> rows chunk*8..+7
      int idx = chunk * 64 + lane;       // row = idx>>3, colgrp = idx&7
      gload16(Bsrc + (size_t)(idx >> 3) * SD + k0 + (idx & 7) * 8,
              (char*)&lsB[buf][0] + chunk * 1024);
    }
  };
  auto awrite = [&](int buf, s8v a0, s8v a1, float w0, float w1) {
    s8v o0, o1;
#pragma unroll
    for (int u = 0; u < 8; ++u) {
      o0[u] = f2bf(bf2f(a0[u]) * w0);
      o1[u] = f2bf(bf2f(a1[u]) * w1);
    }
    *(s8v*)((char*)&lsA[buf][0] + tid * 16) = o0;         // row arow0
    *(s8v*)((char*)&lsA[buf][0] + 4096 + tid * 16) = o1;  // row arow1
  };

  // ---- prologue: stage t=0 into buf 0 ----
  {
    s8v a0 = *(const s8v*)(Asrc + (size_t)arow0 * SD + acb);
    s8v a1 = *(const s8v*)(Asrc + (size_t)arow1 * SD + acb);
    bstage(0, 0);
    awrite(0, a0, a1, w0v[0], w1v[0]);
  }
  __syncthreads();

#pragma unroll 2
  for (int t = 0; t < 32; ++t) {
    int cur = t & 1;
    // ---- issue next-tile prefetch BEFORE compute ----
    s8v na0, na1;
    if (t + 1 < 32) {
      int tn = t + 1;
      int k0n = (tn >> 3) * 512 + (tn & 7) * 64;
      na0 = *(const s8v*)(Asrc + (size_t)arow0 * SD + k0n + acb);
      na1 = *(const s8v*)(Asrc + (size_t)arow1 * SD + k0n + acb);
      bstage(cur ^ 1, k0n);
    }
    // ---- MFMA on current buffers (hides prefetch latency) ----
    const s8v* fA = (const s8v*)&lsA[cur][0];
    const s8v* fB = (const s8v*)&lsB[cur][0];
#pragma unroll
    for (int kk = 0; kk < 2; ++kk) {
      s8v af[4], bq[4];
#pragma unroll
      for (int i = 0; i < 4; ++i) af[i] = fA[(i * 16 + llo) * 8 + kk * 4 + lhi];
#pragma unroll
      for (int j = 0; j < 4; ++j) bq[j] = fB[(wid * 64 + j * 16 + llo) * 8 + kk * 4 + lhi];
#pragma unroll
      for (int i = 0; i < 4; ++i)
#pragma unroll
        for (int j = 0; j < 4; ++j) acc[i][j] = MFMA_BF16(af[i], bq[j], acc[i][j]);
    }
    // ---- write-late: weight-mul A and publish into next buffer ----
    if (t + 1 < 32) {
      int sln = (t + 1) >> 3;
      awrite(cur ^ 1, na0, na1, w0v[sln], w1v[sln]);
    }
    __syncthreads();   // publishes buf cur^1 (B gload_lds + A ds_write drained)
  }

#pragma unroll
  for (int i = 0; i < 4; ++i)
#pragma unroll
    for (int r = 0; r < 4; ++r) {
      int row = b0 + i * 16 + lhi * 4 + r;
#pragma unroll
      for (int j = 0; j < 4; ++j) {
        int col = n0 + wid * 64 + j * 16 + llo;
        yp[(size_t)row * NE + col] = acc[i][j][r];
      }
    }
}

// ---------------------------------------------------------------------------
// K6: y = sum_kg y_part[kg]   (2M f32, f4v per thread)
// ---------------------------------------------------------------------------
__global__ __launch_bounds__(256) void k_reduce(const float* __restrict__ y_part,
                                                float* __restrict__ y) {
  size_t f = ((size_t)blockIdx.x * 256 + threadIdx.x) * 4;   // 2048x256 grid
  f4v acc = *(const f4v*)(y_part + f);
#pragma unroll
  for (int kg = 1; kg < 8; ++kg)
    acc += *(const f4v*)(y_part + (size_t)kg * NB * NE + f);
  *(f4v*)(y + f) = acc;
}

// ---------------------------------------------------------------------------
extern "C" void kernel_launch(void* const* d_in, const int* in_sizes, int n_in,
                              void* d_out, int out_size, void* d_ws, size_t ws_size,
                              hipStream_t stream) {
  const float* x  = (const float*)d_in[0];
  const float* Qw = (const float*)d_in[1];
  const float* Kw = (const float*)d_in[2];
  const float* Vw = (const float*)d_in[3];
  float* y = (float*)d_out;

  char* ws = (char*)d_ws;
  short* xb     = (short*)ws;                                    // 128 MiB
  short* G      = (short*)(ws + (size_t)128 * 1024 * 1024);      // 16 MiB
  short* Vt     = (short*)(ws + (size_t)144 * 1024 * 1024);      // 16 MiB
  short* Ut     = (short*)(ws + (size_t)160 * 1024 * 1024);      // 16 MiB
  float* scores = (float*)(ws + (size_t)176 * 1024 * 1024);      // 512 KiB
  float* wts    = (float*)(ws + (size_t)176 * 1024 * 1024 + 512 * 1024);
  float* y_part = (float*)(ws + (size_t)192 * 1024 * 1024);      // 64 MiB

  k_castx<<<32768, 256, 0, stream>>>(x, xb, scores);
  k_misc<<<2560, 256, 0, stream>>>(Vw, Vt, Kw, Qw, G);
  k_symm<<<dim3(64, NS), 256, 0, stream>>>(G, Ut);
  k_scores<<<2048, 512, 0, stream>>>(xb, Ut, scores);
  k_weights<<<16, 256, 0, stream>>>(scores, wts);
  k_out<<<1024, 256, 0, stream>>>(xb, wts, Vt, y_part);
  k_reduce<<<2048, 256, 0, stream>>>(y_part, y);
}

// Round 16
// 341.851 us; speedup vs baseline: 1.1170x; 1.1170x over previous
//
#include <hip/hip_runtime.h>
#include <hip/hip_bf16.h>
#include <math.h>

// ---------------------------------------------------------------------------
// AttentionBlock: y[b,e] = sum_s w[b,s] * (x_bs @ V_s),
//   w = scores / ||scores||_2,  scores[b,s] = x_bs^T (Q_s K_s^T) x_bs
// Round 16: revert to R13 (best, 351.3us; R15's k_out 2-phase dbuf regressed
// -- occupancy 3->2 cost more than the pipeline bought, matching m99/m132).
// ONE change vs R13: y_part stored as bf16 (64MB+64MB -> 32MB+32MB traffic).
// ---------------------------------------------------------------------------

typedef __attribute__((ext_vector_type(8))) short s8v;   // 8 x bf16 bits
typedef __attribute__((ext_vector_type(4))) float f4v;   // 4 x f32

#define MFMA_BF16(a, b, c) __builtin_amdgcn_mfma_f32_16x16x32_bf16((a), (b), (c), 0, 0, 0)

constexpr int NB = 4096;     // batch
constexpr int NS = 32;       // segments
constexpr int ND = 512;      // d per segment
constexpr int NE = 512;      // e (output dim)
constexpr int SD = NS * ND;  // 16384

__device__ __forceinline__ short f2bf(float f) {
  union { float f; unsigned u; } v; v.f = f;
  unsigned r = v.u + 0x7fffu + ((v.u >> 16) & 1u);  // RNE
  return (short)(r >> 16);
}
__device__ __forceinline__ float bf2f(short h) {
  union { unsigned u; float f; } v; v.u = ((unsigned)(unsigned short)h) << 16;
  return v.f;
}
__device__ __forceinline__ s8v cvt8(const float* p) {
  s8v r;
#pragma unroll
  for (int i = 0; i < 8; ++i) r[i] = f2bf(p[i]);
  return r;
}

// global -> LDS direct (16B per lane). LDS base must be wave-uniform;
// hardware writes base + lane*16 for the wave's 64 lanes.
__device__ __forceinline__ void gload16(const void* g, void* l) {
  __builtin_amdgcn_global_load_lds(
      (const __attribute__((address_space(1))) unsigned int*)g,
      (__attribute__((address_space(3))) unsigned int*)l, 16, 0, 0);
}

// ---------------------------------------------------------------------------
// K_castx: x f32 -> xb bf16 (one vec8/thread, zero LDS) + zero scores
// ---------------------------------------------------------------------------
__global__ __launch_bounds__(256) void k_castx(const float* __restrict__ x,
                                               short* __restrict__ xb,
                                               float* __restrict__ scores) {
  size_t gtid = (size_t)blockIdx.x * 256 + threadIdx.x;
  if (gtid < (size_t)NB * NS / 4) {           // 32768 threads x 4 floats
    f4v z = (f4v)0.0f;
    *(f4v*)(scores + gtid * 4) = z;
  }
  size_t i = gtid * 8;                        // covers exactly NB*SD = 67.1M
  f4v a = *(const f4v*)(x + i);
  f4v b = *(const f4v*)(x + i + 4);
  s8v o;
#pragma unroll
  for (int u = 0; u < 4; ++u) { o[u] = f2bf(a[u]); o[4 + u] = f2bf(b[u]); }
  *(s8v*)(xb + i) = o;
}

// ---------------------------------------------------------------------------
// K_misc: [0,512) gram | [512,2560) transposeV
// ---------------------------------------------------------------------------
__global__ __launch_bounds__(256) void k_misc(const float* __restrict__ V,
                                              short* __restrict__ Vt,
                                              const float* __restrict__ Kw,
                                              const float* __restrict__ Qw,
                                              short* __restrict__ G) {
  __shared__ __align__(16) char smem[36864];
  int bid = blockIdx.x;
  int tid = threadIdx.x;

  if (bid >= 512) {
    // ---- transposeV: V [SD,NE] f32 -> Vt [NE,SD] bf16 ----
    float (*t)[65] = (float(*)[65])smem;
    int t2 = bid - 512;
    int k0 = (t2 & 255) * 64;
    int e0 = (t2 >> 8) * 64;
#pragma unroll
    for (int i = 0; i < 16; ++i) {
      int idx = tid + 256 * i;
      int r = idx >> 6, c = idx & 63;
      t[r][c] = V[(size_t)(k0 + r) * NE + e0 + c];
    }
    __syncthreads();
#pragma unroll
    for (int i = 0; i < 16; ++i) {
      int idx = tid + 256 * i;
      int e = idx >> 6, k = idx & 63;
      Vt[(size_t)(e0 + e) * SD + k0 + k] = f2bf(t[k][e]);
    }
  } else {
    // ---- gram: G_s[i][j] = sum_e K_s[i,e] * Q_s[j,e], 128x128 tile ----
    int t3 = bid;
    int s = t3 >> 4;
    int tm = (t3 >> 2) & 3, tn = t3 & 3;
    const float* A = Kw + (size_t)s * ND * NE + (size_t)tm * 128 * NE;
    const float* B = Qw + (size_t)s * ND * NE + (size_t)tn * 128 * NE;
    short* Gs = G + (size_t)s * ND * ND;

    s8v (*lsA)[9] = (s8v(*)[9])smem;
    s8v (*lsB)[9] = (s8v(*)[9])(smem + 18432);

    int lane = tid & 63, wid = tid >> 6;
    int wr = wid >> 1, wc = wid & 1;
    int lhi = lane >> 4, llo = lane & 15;

    float ra[4][8], rb[4][8];
    f4v acc[4][4];
#pragma unroll
    for (int i = 0; i < 4; ++i)
#pragma unroll
      for (int j = 0; j < 4; ++j) acc[i][j] = (f4v)0.0f;

    auto loadRegs = [&](int k0) {
#pragma unroll
      for (int i = 0; i < 4; ++i) {
        int c = tid + 256 * i; int row = c >> 3, k8 = c & 7;
        const float* p = A + (size_t)row * NE + k0 + k8 * 8;
        *(f4v*)&ra[i][0] = *(const f4v*)p;
        *(f4v*)&ra[i][4] = *(const f4v*)(p + 4);
        const float* q = B + (size_t)row * NE + k0 + k8 * 8;
        *(f4v*)&rb[i][0] = *(const f4v*)q;
        *(f4v*)&rb[i][4] = *(const f4v*)(q + 4);
      }
    };
    auto writeLds = [&]() {
#pragma unroll
      for (int i = 0; i < 4; ++i) {
        int c = tid + 256 * i; int row = c >> 3, k8 = c & 7;
        lsA[row][k8] = cvt8(ra[i]);
        lsB[row][k8] = cvt8(rb[i]);
      }
    };

    loadRegs(0);
    writeLds();
    for (int kt = 0; kt < 8; ++kt) {
      __syncthreads();
      if (kt + 1 < 8) loadRegs((kt + 1) * 64);
#pragma unroll
      for (int kk = 0; kk < 2; ++kk) {
        s8v af[4], bq[4];
#pragma unroll
        for (int i = 0; i < 4; ++i) af[i] = lsA[wr * 64 + i * 16 + llo][kk * 4 + lhi];
#pragma unroll
        for (int j = 0; j < 4; ++j) bq[j] = lsB[wc * 64 + j * 16 + llo][kk * 4 + lhi];
#pragma unroll
        for (int i = 0; i < 4; ++i)
#pragma unroll
          for (int j = 0; j < 4; ++j) acc[i][j] = MFMA_BF16(af[i], bq[j], acc[i][j]);
      }
      __syncthreads();
      if (kt + 1 < 8) writeLds();
    }

#pragma unroll
    for (int i = 0; i < 4; ++i)
#pragma unroll
      for (int r = 0; r < 4; ++r) {
        int row = tm * 128 + wr * 64 + i * 16 + lhi * 4 + r;
#pragma unroll
        for (int j = 0; j < 4; ++j) {
          int col = tn * 128 + wc * 64 + j * 16 + llo;
          Gs[(size_t)row * ND + col] = f2bf(acc[i][j][r]);
        }
      }
  }
}

// ---------------------------------------------------------------------------
// K_symm: U[a][b] = a<b ? G[a][b]+G[b][a] : (a==b ? G[a][a] : 0)
// ---------------------------------------------------------------------------
__global__ __launch_bounds__(256) void k_symm(const short* __restrict__ G,
                                              short* __restrict__ U) {
  int s = blockIdx.y;
  int kt = blockIdx.x >> 3, nt = blockIdx.x & 7;
  const short* Gs = G + (size_t)s * ND * ND;
  short* Us = U + (size_t)s * ND * ND;
  int k0 = kt * 64, n0 = nt * 64;
  int tid = threadIdx.x;
  int r = tid >> 2, cb = (tid & 3) * 16;

  if (kt > nt) {  // strictly below diagonal: zero
    s8v z = (s8v)(short)0;
    *(s8v*)&Us[(size_t)(k0 + r) * ND + n0 + cb] = z;
    *(s8v*)&Us[(size_t)(k0 + r) * ND + n0 + cb + 8] = z;
    return;
  }

  // tt[j][i] = G[n0+j][k0+i]
  __shared__ float tt[64][65];
  {
    const short* src = &Gs[(size_t)(n0 + r) * ND + k0 + cb];
    s8v a = *(const s8v*)src;
    s8v b = *(const s8v*)(src + 8);
#pragma unroll
    for (int u = 0; u < 8; ++u) { tt[r][cb + u] = bf2f(a[u]); tt[r][cb + 8 + u] = bf2f(b[u]); }
  }
  __syncthreads();
  {
    const short* src = &Gs[(size_t)(k0 + r) * ND + n0 + cb];
    s8v a = *(const s8v*)src;
    s8v b = *(const s8v*)(src + 8);
    s8v oa, ob;
#pragma unroll
    for (int u = 0; u < 8; ++u) {
      int k = k0 + r;
      int n1 = n0 + cb + u, n2 = n0 + cb + 8 + u;
      float g1 = bf2f(a[u]), g2 = bf2f(b[u]);
      float v1 = (k < n1) ? (g1 + tt[cb + u][r]) : ((k == n1) ? g1 : 0.f);
      float v2 = (k < n2) ? (g2 + tt[cb + 8 + u][r]) : ((k == n2) ? g2 : 0.f);
      oa[u] = f2bf(v1); ob[u] = f2bf(v2);
    }
    short* dst = &Us[(size_t)(k0 + r) * ND + n0 + cb];
    *(s8v*)dst = oa;
    *(s8v*)(dst + 8) = ob;
  }
}

// ---------------------------------------------------------------------------
// K3: T = Xb_s @ W (W[k][n] = U[n][k], nonzero k >= n),
//     scores[b,s] += sum_n Xb_s[b,n]*T[b,n]
//     256x128 tile, 8 waves (512 thr), BK=64, K-loop kt in [2*nt, 8)
// ---------------------------------------------------------------------------
__global__ __launch_bounds__(512, 4) void k_scores(const short* __restrict__ xb,
                                                   const short* __restrict__ U,
                                                   float* __restrict__ scores) {
  // grid 2048 = 32 s x 16 mt x 4 nt, XCD-chunked by s
  int t = blockIdx.x;
  int swz = (t & 7) * 256 + (t >> 3);     // bijective, 2048 % 8 == 0
  int s = swz >> 6;
  int mt = (swz >> 2) & 15;
  int nt = swz & 3;
  int b0 = mt * 256, n0 = nt * 128;
  const short* Asrc = xb + (size_t)b0 * SD + s * ND;              // LD = SD
  const short* Bt = U + (size_t)s * ND * ND + (size_t)n0 * ND;    // rows = n

  __shared__ __align__(16) short lsA[256 * 64];   // 32 KB
  __shared__ __align__(16) short lsB[128 * 64];   // 16 KB

  int tid = threadIdx.x;
  int lane = tid & 63, wid = tid >> 6;            // 8 waves
  int wr = wid >> 1, wc = wid & 1;                // 4 x 2 wave grid
  int lhi = lane >> 4, llo = lane & 15;
  int lrow = lane >> 3, lcol = (lane & 7) * 8;

  f4v acc[4][4];
#pragma unroll
  for (int i = 0; i < 4; ++i)
#pragma unroll
    for (int j = 0; j < 4; ++j) acc[i][j] = (f4v)0.0f;

  for (int kt = 2 * nt; kt < 8; ++kt) {
    int k0 = kt * 64;
    // A: 32 chunks of 8 rows (4 per wave); B: 16 chunks (2 per wave)
#pragma unroll
    for (int c = 0; c < 4; ++c) {
      int chunk = wid * 4 + c;                 // 0..31
      int row = chunk * 8 + lrow;
      gload16(Asrc + (size_t)row * SD + k0 + lcol, (char*)lsA + chunk * 1024);
    }
#pragma unroll
    for (int c = 0; c < 2; ++c) {
      int chunk = wid * 2 + c;                 // 0..15
      int row = chunk * 8 + lrow;
      gload16(Bt + (size_t)row * ND + k0 + lcol, (char*)lsB + chunk * 1024);
    }
    __syncthreads();
    const s8v* fA = (const s8v*)lsA;
    const s8v* fB = (const s8v*)lsB;
#pragma unroll
    for (int kk = 0; kk < 2; ++kk) {
      s8v af[4], bq[4];
#pragma unroll
      for (int i = 0; i < 4; ++i) af[i] = fA[(wr * 64 + i * 16 + llo) * 8 + kk * 4 + lhi];
#pragma unroll
      for (int j = 0; j < 4; ++j) bq[j] = fB[(wc * 64 + j * 16 + llo) * 8 + kk * 4 + lhi];
#pragma unroll
      for (int i = 0; i < 4; ++i)
#pragma unroll
        for (int j = 0; j < 4; ++j) acc[i][j] = MFMA_BF16(af[i], bq[j], acc[i][j]);
    }
    __syncthreads();
  }

  // Fused epilogue: scores[b,s] += sum over this block's n-range of x*T
#pragma unroll
  for (int i = 0; i < 4; ++i)
#pragma unroll
    for (int r = 0; r < 4; ++r) {
      int rowl = wr * 64 + i * 16 + lhi * 4 + r;
      int b = b0 + rowl;
      const short* xr = xb + (size_t)b * SD + s * ND + n0 + wc * 64;
      float v = 0.f;
#pragma unroll
      for (int j = 0; j < 4; ++j) v += bf2f(xr[j * 16 + llo]) * acc[i][j][r];
      v += __shfl_xor(v, 1);
      v += __shfl_xor(v, 2);
      v += __shfl_xor(v, 4);
      v += __shfl_xor(v, 8);
      if (llo == 0) atomicAdd(&scores[b * NS + s], v);
    }
}

// ---------------------------------------------------------------------------
// K4: weights = scores / ||scores||_2   (grid 16 x 256 = NB threads)
// ---------------------------------------------------------------------------
__global__ __launch_bounds__(256) void k_weights(const float* __restrict__ scores,
                                                 float* __restrict__ w) {
  int b = blockIdx.x * 256 + threadIdx.x;
  float sq = 0.f, sc[NS];
#pragma unroll
  for (int s = 0; s < NS; ++s) { sc[s] = scores[b * NS + s]; sq += sc[s] * sc[s]; }
  float inv = 1.0f / sqrtf(sq);
#pragma unroll
  for (int s = 0; s < NS; ++s) w[b * NS + s] = sc[s] * inv;
}

// ---------------------------------------------------------------------------
// K5: y_part[kg] = (w (.) xb)_kg @ Vt^T_kg   64x256 tile, BK=64, kg = XCD
//     Non-atomic bf16 stores: each block owns a unique (mt,nt,kg) region.
// ---------------------------------------------------------------------------
__global__ __launch_bounds__(256, 3) void k_out(const short* __restrict__ xb,
                                                const float* __restrict__ wts,
                                                const short* __restrict__ Vt,
                                                short* __restrict__ y_part) {
  int t = blockIdx.x;
  int kg = t & 7;                // fastest -> XCD id
  int nt = (t >> 3) & 1;
  int mt = t >> 4;
  int b0 = mt * 64, n0 = nt * 256;
  const short* Asrc = xb + (size_t)b0 * SD + kg * 2048;
  const short* Bsrc = Vt + (size_t)n0 * SD + kg * 2048;   // 256 e-rows, LD = SD
  short* yp = y_part + (size_t)kg * NB * NE;

  __shared__ __align__(16) short lsA[64 * 64];    // 8 KB
  __shared__ __align__(16) short lsB[256 * 64];   // 32 KB

  int tid = threadIdx.x;
  int lane = tid & 63, wid = tid >> 6;            // 4 waves: 1M x 4N
  int lhi = lane >> 4, llo = lane & 15;

  int arow0 = tid >> 3;            // 0..31
  int arow1 = 32 + (tid >> 3);     // 32..63
  int acb = (tid & 7) * 8;         // col offset (elements)

  f4v acc[4][4];
#pragma unroll
  for (int i = 0; i < 4; ++i)
#pragma unroll
    for (int j = 0; j < 4; ++j) acc[i][j] = (f4v)0.0f;

  for (int sl = 0; sl < 4; ++sl) {
    int s = kg * 4 + sl;
    float w0 = wts[(b0 + arow0) * NS + s];
    float w1 = wts[(b0 + arow1) * NS + s];
#pragma unroll 1
    for (int k8 = 0; k8 < 8; ++k8) {
      int k0 = sl * 512 + k8 * 64;
      // B: each wave stages its own quarter (rows wid*64 .. wid*64+63)
#pragma unroll
      for (int c = 0; c < 8; ++c) {
        int chunk = wid * 8 + c;           // 0..31 -> rows chunk*8..+7
        int idx = chunk * 64 + lane;       // row = idx>>3, colgrp = idx&7
        gload16(Bsrc + (size_t)(idx >> 3) * SD + k0 + (idx & 7) * 8,
                (char*)lsB + chunk * 1024);
      }
      // A: reg-stage 2 x 16B with weight applied
      s8v a0 = *(const s8v*)(Asrc + (size_t)arow0 * SD + k0 + acb);
      s8v a1 = *(const s8v*)(Asrc + (size_t)arow1 * SD + k0 + acb);
      s8v o0, o1;
#pragma unroll
      for (int u = 0; u < 8; ++u) {
        o0[u] = f2bf(bf2f(a0[u]) * w0);
        o1[u] = f2bf(bf2f(a1[u]) * w1);
      }
      *(s8v*)((char*)lsA + tid * 16) = o0;         // row arow0
      *(s8v*)((char*)lsA + 4096 + tid * 16) = o1;  // row arow1
      __syncthreads();   // drains vmcnt (B) + lgkm (A writes)
      const s8v* fA = (const s8v*)lsA;
      const s8v* fB = (const s8v*)lsB;
#pragma unroll
      for (int kk = 0; kk < 2; ++kk) {
        s8v af[4], bq[4];
#pragma unroll
        for (int i = 0; i < 4; ++i) af[i] = fA[(i * 16 + llo) * 8 + kk * 4 + lhi];
#pragma unroll
        for (int j = 0; j < 4; ++j) bq[j] = fB[(wid * 64 + j * 16 + llo) * 8 + kk * 4 + lhi];
#pragma unroll
        for (int i = 0; i < 4; ++i)
#pragma unroll
          for (int j = 0; j < 4; ++j) acc[i][j] = MFMA_BF16(af[i], bq[j], acc[i][j]);
      }
      __syncthreads();
    }
  }

#pragma unroll
  for (int i = 0; i < 4; ++i)
#pragma unroll
    for (int r = 0; r < 4; ++r) {
      int row = b0 + i * 16 + lhi * 4 + r;
#pragma unroll
      for (int j = 0; j < 4; ++j) {
        int col = n0 + wid * 64 + j * 16 + llo;
        yp[(size_t)row * NE + col] = f2bf(acc[i][j][r]);
      }
    }
}

// ---------------------------------------------------------------------------
// K6: y = sum_kg y_part[kg]   (bf16 partials, 8 elems/thread)
// ---------------------------------------------------------------------------
__global__ __launch_bounds__(256) void k_reduce(const short* __restrict__ y_part,
                                                float* __restrict__ y) {
  size_t f = ((size_t)blockIdx.x * 256 + threadIdx.x) * 8;   // 1024x256 grid
  float acc[8];
#pragma unroll
  for (int u = 0; u < 8; ++u) acc[u] = 0.f;
#pragma unroll
  for (int kg = 0; kg < 8; ++kg) {
    s8v v = *(const s8v*)(y_part + (size_t)kg * NB * NE + f);
#pragma unroll
    for (int u = 0; u < 8; ++u) acc[u] += bf2f(v[u]);
  }
  *(f4v*)(y + f) = *(f4v*)&acc[0];
  *(f4v*)(y + f + 4) = *(f4v*)&acc[4];
}

// ---------------------------------------------------------------------------
extern "C" void kernel_launch(void* const* d_in, const int* in_sizes, int n_in,
                              void* d_out, int out_size, void* d_ws, size_t ws_size,
                              hipStream_t stream) {
  const float* x  = (const float*)d_in[0];
  const float* Qw = (const float*)d_in[1];
  const float* Kw = (const float*)d_in[2];
  const float* Vw = (const float*)d_in[3];
  float* y = (float*)d_out;

  char* ws = (char*)d_ws;
  short* xb     = (short*)ws;                                    // 128 MiB
  short* G      = (short*)(ws + (size_t)128 * 1024 * 1024);      // 16 MiB
  short* Vt     = (short*)(ws + (size_t)144 * 1024 * 1024);      // 16 MiB
  short* Ut     = (short*)(ws + (size_t)160 * 1024 * 1024);      // 16 MiB
  float* scores = (float*)(ws + (size_t)176 * 1024 * 1024);      // 512 KiB
  float* wts    = (float*)(ws + (size_t)176 * 1024 * 1024 + 512 * 1024);
  short* y_part = (short*)(ws + (size_t)192 * 1024 * 1024);      // 32 MiB (bf16)

  k_castx<<<32768, 256, 0, stream>>>(x, xb, scores);
  k_misc<<<2560, 256, 0, stream>>>(Vw, Vt, Kw, Qw, G);
  k_symm<<<dim3(64, NS), 256, 0, stream>>>(G, Ut);
  k_scores<<<2048, 512, 0, stream>>>(xb, Ut, scores);
  k_weights<<<16, 256, 0, stream>>>(scores, wts);
  k_out<<<1024, 256, 0, stream>>>(xb, wts, Vt, y_part);
  k_reduce<<<1024, 256, 0, stream>>>(y_part, y);
}

// Round 17
// 318.111 us; speedup vs baseline: 1.2004x; 1.0746x over previous
//
#include <hip/hip_runtime.h>
#include <hip/hip_bf16.h>
#include <math.h>

// ---------------------------------------------------------------------------
// AttentionBlock: y[b,e] = sum_s w[b,s] * (x_bs @ V_s),
//   w = scores / ||scores||_2,  scores[b,s] = x_bs^T (Q_s K_s^T) x_bs
// Round 17: R16 base (best, 341.9us) + T2 XOR-swizzle on k_scores/k_out LDS.
//   Fragment reads had row-stride 128B = 32 banks -> 16-way conflict on every
//   ds_read_b128 (SQ_LDS_BANK_CONFLICT 2.5e7). Fix per rule #21: linear LDS
//   dest (gload_lds) + pre-swizzled GLOBAL source colgrp ((lane&7)^(lane>>3))
//   + XOR'd read index (cc ^ (row&7)). k_out's reg-staged A swizzles its
//   ds_write directly. Involution: slot(row,pc) holds pc^(row&7).
// ---------------------------------------------------------------------------

typedef __attribute__((ext_vector_type(8))) short s8v;   // 8 x bf16 bits
typedef __attribute__((ext_vector_type(4))) float f4v;   // 4 x f32

#define MFMA_BF16(a, b, c) __builtin_amdgcn_mfma_f32_16x16x32_bf16((a), (b), (c), 0, 0, 0)

constexpr int NB = 4096;     // batch
constexpr int NS = 32;       // segments
constexpr int ND = 512;      // d per segment
constexpr int NE = 512;      // e (output dim)
constexpr int SD = NS * ND;  // 16384

__device__ __forceinline__ short f2bf(float f) {
  union { float f; unsigned u; } v; v.f = f;
  unsigned r = v.u + 0x7fffu + ((v.u >> 16) & 1u);  // RNE
  return (short)(r >> 16);
}
__device__ __forceinline__ float bf2f(short h) {
  union { unsigned u; float f; } v; v.u = ((unsigned)(unsigned short)h) << 16;
  return v.f;
}
__device__ __forceinline__ s8v cvt8(const float* p) {
  s8v r;
#pragma unroll
  for (int i = 0; i < 8; ++i) r[i] = f2bf(p[i]);
  return r;
}

// global -> LDS direct (16B per lane). LDS base must be wave-uniform;
// hardware writes base + lane*16 for the wave's 64 lanes.
__device__ __forceinline__ void gload16(const void* g, void* l) {
  __builtin_amdgcn_global_load_lds(
      (const __attribute__((address_space(1))) unsigned int*)g,
      (__attribute__((address_space(3))) unsigned int*)l, 16, 0, 0);
}

// ---------------------------------------------------------------------------
// K_castx: x f32 -> xb bf16 (one vec8/thread, zero LDS) + zero scores
// ---------------------------------------------------------------------------
__global__ __launch_bounds__(256) void k_castx(const float* __restrict__ x,
                                               short* __restrict__ xb,
                                               float* __restrict__ scores) {
  size_t gtid = (size_t)blockIdx.x * 256 + threadIdx.x;
  if (gtid < (size_t)NB * NS / 4) {           // 32768 threads x 4 floats
    f4v z = (f4v)0.0f;
    *(f4v*)(scores + gtid * 4) = z;
  }
  size_t i = gtid * 8;                        // covers exactly NB*SD = 67.1M
  f4v a = *(const f4v*)(x + i);
  f4v b = *(const f4v*)(x + i + 4);
  s8v o;
#pragma unroll
  for (int u = 0; u < 4; ++u) { o[u] = f2bf(a[u]); o[4 + u] = f2bf(b[u]); }
  *(s8v*)(xb + i) = o;
}

// ---------------------------------------------------------------------------
// K_misc: [0,512) gram | [512,2560) transposeV
// ---------------------------------------------------------------------------
__global__ __launch_bounds__(256) void k_misc(const float* __restrict__ V,
                                              short* __restrict__ Vt,
                                              const float* __restrict__ Kw,
                                              const float* __restrict__ Qw,
                                              short* __restrict__ G) {
  __shared__ __align__(16) char smem[36864];
  int bid = blockIdx.x;
  int tid = threadIdx.x;

  if (bid >= 512) {
    // ---- transposeV: V [SD,NE] f32 -> Vt [NE,SD] bf16 ----
    float (*t)[65] = (float(*)[65])smem;
    int t2 = bid - 512;
    int k0 = (t2 & 255) * 64;
    int e0 = (t2 >> 8) * 64;
#pragma unroll
    for (int i = 0; i < 16; ++i) {
      int idx = tid + 256 * i;
      int r = idx >> 6, c = idx & 63;
      t[r][c] = V[(size_t)(k0 + r) * NE + e0 + c];
    }
    __syncthreads();
#pragma unroll
    for (int i = 0; i < 16; ++i) {
      int idx = tid + 256 * i;
      int e = idx >> 6, k = idx & 63;
      Vt[(size_t)(e0 + e) * SD + k0 + k] = f2bf(t[k][e]);
    }
  } else {
    // ---- gram: G_s[i][j] = sum_e K_s[i,e] * Q_s[j,e], 128x128 tile ----
    int t3 = bid;
    int s = t3 >> 4;
    int tm = (t3 >> 2) & 3, tn = t3 & 3;
    const float* A = Kw + (size_t)s * ND * NE + (size_t)tm * 128 * NE;
    const float* B = Qw + (size_t)s * ND * NE + (size_t)tn * 128 * NE;
    short* Gs = G + (size_t)s * ND * ND;

    s8v (*lsA)[9] = (s8v(*)[9])smem;
    s8v (*lsB)[9] = (s8v(*)[9])(smem + 18432);

    int lane = tid & 63, wid = tid >> 6;
    int wr = wid >> 1, wc = wid & 1;
    int lhi = lane >> 4, llo = lane & 15;

    float ra[4][8], rb[4][8];
    f4v acc[4][4];
#pragma unroll
    for (int i = 0; i < 4; ++i)
#pragma unroll
      for (int j = 0; j < 4; ++j) acc[i][j] = (f4v)0.0f;

    auto loadRegs = [&](int k0) {
#pragma unroll
      for (int i = 0; i < 4; ++i) {
        int c = tid + 256 * i; int row = c >> 3, k8 = c & 7;
        const float* p = A + (size_t)row * NE + k0 + k8 * 8;
        *(f4v*)&ra[i][0] = *(const f4v*)p;
        *(f4v*)&ra[i][4] = *(const f4v*)(p + 4);
        const float* q = B + (size_t)row * NE + k0 + k8 * 8;
        *(f4v*)&rb[i][0] = *(const f4v*)q;
        *(f4v*)&rb[i][4] = *(const f4v*)(q + 4);
      }
    };
    auto writeLds = [&]() {
#pragma unroll
      for (int i = 0; i < 4; ++i) {
        int c = tid + 256 * i; int row = c >> 3, k8 = c & 7;
        lsA[row][k8] = cvt8(ra[i]);
        lsB[row][k8] = cvt8(rb[i]);
      }
    };

    loadRegs(0);
    writeLds();
    for (int kt = 0; kt < 8; ++kt) {
      __syncthreads();
      if (kt + 1 < 8) loadRegs((kt + 1) * 64);
#pragma unroll
      for (int kk = 0; kk < 2; ++kk) {
        s8v af[4], bq[4];
#pragma unroll
        for (int i = 0; i < 4; ++i) af[i] = lsA[wr * 64 + i * 16 + llo][kk * 4 + lhi];
#pragma unroll
        for (int j = 0; j < 4; ++j) bq[j] = lsB[wc * 64 + j * 16 + llo][kk * 4 + lhi];
#pragma unroll
        for (int i = 0; i < 4; ++i)
#pragma unroll
          for (int j = 0; j < 4; ++j) acc[i][j] = MFMA_BF16(af[i], bq[j], acc[i][j]);
      }
      __syncthreads();
      if (kt + 1 < 8) writeLds();
    }

#pragma unroll
    for (int i = 0; i < 4; ++i)
#pragma unroll
      for (int r = 0; r < 4; ++r) {
        int row = tm * 128 + wr * 64 + i * 16 + lhi * 4 + r;
#pragma unroll
        for (int j = 0; j < 4; ++j) {
          int col = tn * 128 + wc * 64 + j * 16 + llo;
          Gs[(size_t)row * ND + col] = f2bf(acc[i][j][r]);
        }
      }
  }
}

// ---------------------------------------------------------------------------
// K_symm: U[a][b] = a<b ? G[a][b]+G[b][a] : (a==b ? G[a][a] : 0)
// ---------------------------------------------------------------------------
__global__ __launch_bounds__(256) void k_symm(const short* __restrict__ G,
                                              short* __restrict__ U) {
  int s = blockIdx.y;
  int kt = blockIdx.x >> 3, nt = blockIdx.x & 7;
  const short* Gs = G + (size_t)s * ND * ND;
  short* Us = U + (size_t)s * ND * ND;
  int k0 = kt * 64, n0 = nt * 64;
  int tid = threadIdx.x;
  int r = tid >> 2, cb = (tid & 3) * 16;

  if (kt > nt) {  // strictly below diagonal: zero
    s8v z = (s8v)(short)0;
    *(s8v*)&Us[(size_t)(k0 + r) * ND + n0 + cb] = z;
    *(s8v*)&Us[(size_t)(k0 + r) * ND + n0 + cb + 8] = z;
    return;
  }

  // tt[j][i] = G[n0+j][k0+i]
  __shared__ float tt[64][65];
  {
    const short* src = &Gs[(size_t)(n0 + r) * ND + k0 + cb];
    s8v a = *(const s8v*)src;
    s8v b = *(const s8v*)(src + 8);
#pragma unroll
    for (int u = 0; u < 8; ++u) { tt[r][cb + u] = bf2f(a[u]); tt[r][cb + 8 + u] = bf2f(b[u]); }
  }
  __syncthreads();
  {
    const short* src = &Gs[(size_t)(k0 + r) * ND + n0 + cb];
    s8v a = *(const s8v*)src;
    s8v b = *(const s8v*)(src + 8);
    s8v oa, ob;
#pragma unroll
    for (int u = 0; u < 8; ++u) {
      int k = k0 + r;
      int n1 = n0 + cb + u, n2 = n0 + cb + 8 + u;
      float g1 = bf2f(a[u]), g2 = bf2f(b[u]);
      float v1 = (k < n1) ? (g1 + tt[cb + u][r]) : ((k == n1) ? g1 : 0.f);
      float v2 = (k < n2) ? (g2 + tt[cb + 8 + u][r]) : ((k == n2) ? g2 : 0.f);
      oa[u] = f2bf(v1); ob[u] = f2bf(v2);
    }
    short* dst = &Us[(size_t)(k0 + r) * ND + n0 + cb];
    *(s8v*)dst = oa;
    *(s8v*)(dst + 8) = ob;
  }
}

// ---------------------------------------------------------------------------
// K3: T = Xb_s @ W (W[k][n] = U[n][k], nonzero k >= n),
//     scores[b,s] += sum_n Xb_s[b,n]*T[b,n]
//     256x128 tile, 8 waves, BK=64, K-loop kt in [2*nt, 8), T2-swizzled LDS
// ---------------------------------------------------------------------------
__global__ __launch_bounds__(512, 4) void k_scores(const short* __restrict__ xb,
                                                   const short* __restrict__ U,
                                                   float* __restrict__ scores) {
  // grid 2048 = 32 s x 16 mt x 4 nt, XCD-chunked by s
  int t = blockIdx.x;
  int swz = (t & 7) * 256 + (t >> 3);     // bijective, 2048 % 8 == 0
  int s = swz >> 6;
  int mt = (swz >> 2) & 15;
  int nt = swz & 3;
  int b0 = mt * 256, n0 = nt * 128;
  const short* Asrc = xb + (size_t)b0 * SD + s * ND;              // LD = SD
  const short* Bt = U + (size_t)s * ND * ND + (size_t)n0 * ND;    // rows = n

  __shared__ __align__(16) short lsA[256 * 64];   // 32 KB
  __shared__ __align__(16) short lsB[128 * 64];   // 16 KB

  int tid = threadIdx.x;
  int lane = tid & 63, wid = tid >> 6;            // 8 waves
  int wr = wid >> 1, wc = wid & 1;                // 4 x 2 wave grid
  int lhi = lane >> 4, llo = lane & 15;
  int lrow = lane >> 3;
  int scol = ((lane & 7) ^ lrow) * 8;             // pre-swizzled source colgrp

  f4v acc[4][4];
#pragma unroll
  for (int i = 0; i < 4; ++i)
#pragma unroll
    for (int j = 0; j < 4; ++j) acc[i][j] = (f4v)0.0f;

  for (int kt = 2 * nt; kt < 8; ++kt) {
    int k0 = kt * 64;
    // A: 32 chunks of 8 rows (4 per wave); B: 16 chunks (2 per wave)
#pragma unroll
    for (int c = 0; c < 4; ++c) {
      int chunk = wid * 4 + c;                 // 0..31
      int row = chunk * 8 + lrow;
      gload16(Asrc + (size_t)row * SD + k0 + scol, (char*)lsA + chunk * 1024);
    }
#pragma unroll
    for (int c = 0; c < 2; ++c) {
      int chunk = wid * 2 + c;                 // 0..15
      int row = chunk * 8 + lrow;
      gload16(Bt + (size_t)row * ND + k0 + scol, (char*)lsB + chunk * 1024);
    }
    __syncthreads();
    const s8v* fA = (const s8v*)lsA;
    const s8v* fB = (const s8v*)lsB;
#pragma unroll
    for (int kk = 0; kk < 2; ++kk) {
      s8v af[4], bq[4];
      int cc = kk * 4 + lhi;
      int ccs = cc ^ (llo & 7);                // row&7 == llo&7 for all rows
#pragma unroll
      for (int i = 0; i < 4; ++i) af[i] = fA[(wr * 64 + i * 16 + llo) * 8 + ccs];
#pragma unroll
      for (int j = 0; j < 4; ++j) bq[j] = fB[(wc * 64 + j * 16 + llo) * 8 + ccs];
#pragma unroll
      for (int i = 0; i < 4; ++i)
#pragma unroll
        for (int j = 0; j < 4; ++j) acc[i][j] = MFMA_BF16(af[i], bq[j], acc[i][j]);
    }
    __syncthreads();
  }

  // Fused epilogue: scores[b,s] += sum over this block's n-range of x*T
#pragma unroll
  for (int i = 0; i < 4; ++i)
#pragma unroll
    for (int r = 0; r < 4; ++r) {
      int rowl = wr * 64 + i * 16 + lhi * 4 + r;
      int b = b0 + rowl;
      const short* xr = xb + (size_t)b * SD + s * ND + n0 + wc * 64;
      float v = 0.f;
#pragma unroll
      for (int j = 0; j < 4; ++j) v += bf2f(xr[j * 16 + llo]) * acc[i][j][r];
      v += __shfl_xor(v, 1);
      v += __shfl_xor(v, 2);
      v += __shfl_xor(v, 4);
      v += __shfl_xor(v, 8);
      if (llo == 0) atomicAdd(&scores[b * NS + s], v);
    }
}

// ---------------------------------------------------------------------------
// K4: weights = scores / ||scores||_2   (grid 16 x 256 = NB threads)
// ---------------------------------------------------------------------------
__global__ __launch_bounds__(256) void k_weights(const float* __restrict__ scores,
                                                 float* __restrict__ w) {
  int b = blockIdx.x * 256 + threadIdx.x;
  float sq = 0.f, sc[NS];
#pragma unroll
  for (int s = 0; s < NS; ++s) { sc[s] = scores[b * NS + s]; sq += sc[s] * sc[s]; }
  float inv = 1.0f / sqrtf(sq);
#pragma unroll
  for (int s = 0; s < NS; ++s) w[b * NS + s] = sc[s] * inv;
}

// ---------------------------------------------------------------------------
// K5: y_part[kg] = (w (.) xb)_kg @ Vt^T_kg   64x256 tile, BK=64, kg = XCD
//     Non-atomic bf16 stores. T2-swizzled LDS (A via ds_write, B via gload).
// ---------------------------------------------------------------------------
__global__ __launch_bounds__(256, 3) void k_out(const short* __restrict__ xb,
                                                const float* __restrict__ wts,
                                                const short* __restrict__ Vt,
                                                short* __restrict__ y_part) {
  int t = blockIdx.x;
  int kg = t & 7;                // fastest -> XCD id
  int nt = (t >> 3) & 1;
  int mt = t >> 4;
  int b0 = mt * 64, n0 = nt * 256;
  const short* Asrc = xb + (size_t)b0 * SD + kg * 2048;
  const short* Bsrc = Vt + (size_t)n0 * SD + kg * 2048;   // 256 e-rows, LD = SD
  short* yp = y_part + (size_t)kg * NB * NE;

  __shared__ __align__(16) short lsA[64 * 64];    // 8 KB
  __shared__ __align__(16) short lsB[256 * 64];   // 32 KB

  int tid = threadIdx.x;
  int lane = tid & 63, wid = tid >> 6;            // 4 waves: 1M x 4N
  int lhi = lane >> 4, llo = lane & 15;
  int lrow = lane >> 3;
  int scol = ((lane & 7) ^ lrow) * 8;             // pre-swizzled source colgrp

  int arow0 = tid >> 3;            // 0..31
  int arow1 = 32 + (tid >> 3);     // 32..63
  int acb = (tid & 7) * 8;         // A source col offset (elements, unswizzled)
  // swizzled ds_write byte offset for A rows (arow&7 identical for both rows)
  int awoff = (arow0 * 8 + ((tid & 7) ^ (arow0 & 7))) * 16;

  f4v acc[4][4];
#pragma unroll
  for (int i = 0; i < 4; ++i)
#pragma unroll
    for (int j = 0; j < 4; ++j) acc[i][j] = (f4v)0.0f;

  for (int sl = 0; sl < 4; ++sl) {
    int s = kg * 4 + sl;
    float w0 = wts[(b0 + arow0) * NS + s];
    float w1 = wts[(b0 + arow1) * NS + s];
#pragma unroll 1
    for (int k8 = 0; k8 < 8; ++k8) {
      int k0 = sl * 512 + k8 * 64;
      // B: each wave stages its own quarter (rows wid*64 .. wid*64+63)
#pragma unroll
      for (int c = 0; c < 8; ++c) {
        int chunk = wid * 8 + c;           // 0..31 -> rows chunk*8..+7
        int row = chunk * 8 + lrow;
        gload16(Bsrc + (size_t)row * SD + k0 + scol, (char*)lsB + chunk * 1024);
      }
      // A: reg-stage 2 x 16B with weight applied, swizzled ds_write
      s8v a0 = *(const s8v*)(Asrc + (size_t)arow0 * SD + k0 + acb);
      s8v a1 = *(const s8v*)(Asrc + (size_t)arow1 * SD + k0 + acb);
      s8v o0, o1;
#pragma unroll
      for (int u = 0; u < 8; ++u) {
        o0[u] = f2bf(bf2f(a0[u]) * w0);
        o1[u] = f2bf(bf2f(a1[u]) * w1);
      }
      *(s8v*)((char*)lsA + awoff) = o0;          // row arow0 (swizzled slot)
      *(s8v*)((char*)lsA + 4096 + awoff) = o1;   // row arow1 (same &7)
      __syncthreads();   // drains vmcnt (B) + lgkm (A writes)
      const s8v* fA = (const s8v*)lsA;
      const s8v* fB = (const s8v*)lsB;
#pragma unroll
      for (int kk = 0; kk < 2; ++kk) {
        s8v af[4], bq[4];
        int cc = kk * 4 + lhi;
        int ccs = cc ^ (llo & 7);              // row&7 == llo&7
#pragma unroll
        for (int i = 0; i < 4; ++i) af[i] = fA[(i * 16 + llo) * 8 + ccs];
#pragma unroll
        for (int j = 0; j < 4; ++j) bq[j] = fB[(wid * 64 + j * 16 + llo) * 8 + ccs];
#pragma unroll
        for (int i = 0; i < 4; ++i)
#pragma unroll
          for (int j = 0; j < 4; ++j) acc[i][j] = MFMA_BF16(af[i], bq[j], acc[i][j]);
      }
      __syncthreads();
    }
  }

#pragma unroll
  for (int i = 0; i < 4; ++i)
#pragma unroll
    for (int r = 0; r < 4; ++r) {
      int row = b0 + i * 16 + lhi * 4 + r;
#pragma unroll
      for (int j = 0; j < 4; ++j) {
        int col = n0 + wid * 64 + j * 16 + llo;
        yp[(size_t)row * NE + col] = f2bf(acc[i][j][r]);
      }
    }
}

// ---------------------------------------------------------------------------
// K6: y = sum_kg y_part[kg]   (bf16 partials, 8 elems/thread)
// ---------------------------------------------------------------------------
__global__ __launch_bounds__(256) void k_reduce(const short* __restrict__ y_part,
                                                float* __restrict__ y) {
  size_t f = ((size_t)blockIdx.x * 256 + threadIdx.x) * 8;   // 1024x256 grid
  float acc[8];
#pragma unroll
  for (int u = 0; u < 8; ++u) acc[u] = 0.f;
#pragma unroll
  for (int kg = 0; kg < 8; ++kg) {
    s8v v = *(const s8v*)(y_part + (size_t)kg * NB * NE + f);
#pragma unroll
    for (int u = 0; u < 8; ++u) acc[u] += bf2f(v[u]);
  }
  *(f4v*)(y + f) = *(f4v*)&acc[0];
  *(f4v*)(y + f + 4) = *(f4v*)&acc[4];
}

// ---------------------------------------------------------------------------
extern "C" void kernel_launch(void* const* d_in, const int* in_sizes, int n_in,
                              void* d_out, int out_size, void* d_ws, size_t ws_size,
                              hipStream_t stream) {
  const float* x  = (const float*)d_in[0];
  const float* Qw = (const float*)d_in[1];
  const float* Kw = (const float*)d_in[2];
  const float* Vw = (const float*)d_in[3];
  float* y = (float*)d_out;

  char* ws = (char*)d_ws;
  short* xb     = (short*)ws;                                    // 128 MiB
  short* G      = (short*)(ws + (size_t)128 * 1024 * 1024);      // 16 MiB
  short* Vt     = (short*)(ws + (size_t)144 * 1024 * 1024);      // 16 MiB
  short* Ut     = (short*)(ws + (size_t)160 * 1024 * 1024);      // 16 MiB
  float* scores = (float*)(ws + (size_t)176 * 1024 * 1024);      // 512 KiB
  float* wts    = (float*)(ws + (size_t)176 * 1024 * 1024 + 512 * 1024);
  short* y_part = (short*)(ws + (size_t)192 * 1024 * 1024);      // 32 MiB (bf16)

  k_castx<<<32768, 256, 0, stream>>>(x, xb, scores);
  k_misc<<<2560, 256, 0, stream>>>(Vw, Vt, Kw, Qw, G);
  k_symm<<<dim3(64, NS), 256, 0, stream>>>(G, Ut);
  k_scores<<<2048, 512, 0, stream>>>(xb, Ut, scores);
  k_weights<<<16, 256, 0, stream>>>(scores, wts);
  k_out<<<1024, 256, 0, stream>>>(xb, wts, Vt, y_part);
  k_reduce<<<1024, 256, 0, stream>>>(y_part, y);
}